// Round 1
// baseline (67.375 us; speedup 1.0000x reference)
//
#include <hip/hip_runtime.h>
#include <math.h>

#define S_ 8
#define J_ 4
#define D_ 4
#define P_ 3
#define N_ 1024
#define BG_ 32
#define BU_ 32
#define MG_ 10
#define MU_ 32

static constexpr float PI_F = 3.14159265358979323846f;

// workspace float offsets
#define COEF_OFF    0                    // S*J*BU*D*2 = 8192
#define C1_OFF      8192                 // S*D*P*BG  = 3072 (layout [d][p][b][s])
#define C2_OFF      11264                // 3072
#define QUAMP_OFF   14336                // S*D*MU    = 1024 (layout [s][d][m])
#define CANPART_OFF 15360                // S*N*D     = 32768 (layout [s][n][d])

// ---------------- prep: Ghat -> G3 -> coef;  c1/c2 tables;  quAmp -------------
__global__ __launch_bounds__(256) void prep_kernel(
    const float* __restrict__ alphas, const float* __restrict__ pgs,
    const float* __restrict__ zgs,    const float* __restrict__ thetag,
    const float* __restrict__ betag,  const float* __restrict__ wg,
    const float* __restrict__ qg,     const float* __restrict__ pus,
    const float* __restrict__ thetau, const float* __restrict__ betau,
    const float* __restrict__ wu,     const float* __restrict__ qu,
    const float* __restrict__ ampu_p, const float* __restrict__ log_amps,
    float* __restrict__ ws)
{
    int tid = blockIdx.x * blockDim.x + threadIdx.x;
    float ampu = ampu_p[0];

    if (tid < S_*J_*D_*BU_) {                      // 4096: complex coefficients
        int bu = tid & 31, d = (tid >> 5) & 3, j = (tid >> 7) & 3, s = tid >> 9;
        float G3r = 1.f, G3i = 0.f;
        for (int p = 0; p < P_; ++p) {
            float alpha = alphas[d*P_ + p], pg = pgs[d*P_ + p];
            float om    = thetau[((s*J_ + j)*P_ + p)*BU_ + bu];
            float inv4a = 0.25f / alpha;
            float pref  = 0.5f * sqrtf(PI_F / alpha);
            float gr = 0.f, gi = 0.f;
            for (int b = 0; b < BG_; ++b) {
                float th = thetag[(d*P_ + p)*BG_ + b];
                float dm = th - om, dpl = th + om;
                float e1 = __expf(-dm*dm*inv4a);
                float e2 = __expf(-dpl*dpl*inv4a);
                float be = betag[((s*D_ + d)*P_ + p)*BG_ + b];
                float w  = wg   [((s*D_ + d)*P_ + p)*BG_ + b];
                float sb, cb; __sincosf(be, &sb, &cb);
                gr += pref * w * (e1 + e2) * cb;
                gi += pref * w * (e1 - e2) * sb;
            }
            float A = alpha + pg, invA = 1.f / A;
            float decay = __expf(-om*om*0.25f*invA);
            float cc    = sqrtf(PI_F * invA);
            float cr = 0.f, ci = 0.f;
            for (int g = 0; g < MG_; ++g) {
                float z  = zgs[g*P_ + p];
                float mu = pg * z * invA;
                float rg = alpha * pg * z * z * invA;
                float cg = cc * __expf(-rg);
                float q  = qg[((s*D_ + d)*P_ + p)*MG_ + g];
                float sm, cm; __sincosf(om * mu, &sm, &cm);
                cr += q * cg * cm;
                ci -= q * cg * sm;
            }
            float Gr = gr + decay * cr;
            float Gi = gi + decay * ci;
            float nr = G3r*Gr - G3i*Gi;
            float ni = G3r*Gi + G3i*Gr;
            G3r = nr; G3i = ni;
        }
        float bv = betau[(s*J_ + j)*BU_ + bu];
        float wv = wu   [(s*J_ + j)*BU_ + bu];
        float sbu, cbu; __sincosf(bv, &sbu, &cbu);
        float cuR = wv * cbu, cuI = wv * sbu;
        float amp = ampu * __expf(log_amps[d*J_ + j]);
        int base = (((s*J_ + j)*BU_ + bu)*D_ + d) * 2;
        ws[COEF_OFF + base    ] = amp * (cuR*G3r - cuI*G3i);
        ws[COEF_OFF + base + 1] = amp * (cuR*G3i + cuI*G3r);
    } else if (tid < 4096 + S_*D_*P_*BG_) {        // 3072: coef1/coef2 tables
        int id = tid - 4096;                        // id = ((d*P+p)*BG + b)*S + s
        int s = id & 7, b = (id >> 3) & 31, dppi = id >> 8;
        int d = dppi / P_, p = dppi % P_;
        float alpha = alphas[d*P_ + p];
        float Bm = alpha + pus[p];
        float th = thetag[dppi*BG_ + b];
        float spec = sqrtf(PI_F / Bm) * __expf(-th*th*0.25f/Bm);
        float be = betag[((s*D_ + d)*P_ + p)*BG_ + b];
        float w  = wg   [((s*D_ + d)*P_ + p)*BG_ + b];
        float sb, cb; __sincosf(be, &sb, &cb);
        ws[C1_OFF + id] = w * cb * spec;
        ws[C2_OFF + id] = w * sb * spec;
    } else if (tid < 4096 + 3072 + S_*D_*MU_) {    // 1024: quAmp[s][d][m]
        int id = tid - (4096 + 3072);
        int m = id & 31, d = (id >> 5) & 3, s = id >> 7;
        float acc = 0.f;
        for (int j = 0; j < J_; ++j)
            acc += __expf(log_amps[d*J_ + j]) * qu[(s*J_ + j)*MU_ + m];
        ws[QUAMP_OFF + (s*D_ + d)*MU_ + m] = ampu * acc;
    }
}

// ---------------- canonical: Gg product over p, reduce over m ----------------
__global__ __launch_bounds__(256) void can_kernel(
    const float* __restrict__ ts,   const float* __restrict__ alphas,
    const float* __restrict__ pgs,  const float* __restrict__ zgs,
    const float* __restrict__ thetag, const float* __restrict__ qg,
    const float* __restrict__ pus,  const float* __restrict__ zus,
    float* __restrict__ ws)
{
    int tid = blockIdx.x * 256 + threadIdx.x;      // D*N*MU = 131072 threads
    int m = tid & 31;
    int n = (tid >> 5) & (N_ - 1);
    int d = tid >> 15;

    float prod[S_];
    #pragma unroll
    for (int s = 0; s < S_; ++s) prod[s] = 1.f;

    for (int p = 0; p < P_; ++p) {
        float alpha = alphas[d*P_ + p], pg = pgs[d*P_ + p], pu = pus[p];
        float c  = ts[n*P_ + p] - zus[m*P_ + p];
        float Bm = alpha + pu, invB = 1.f / Bm;
        float mp = pu * c * invB;
        float rp = alpha * pu * c * c * invB;
        float E  = __expf(-rp);

        float acc[S_];
        #pragma unroll
        for (int s = 0; s < S_; ++s) acc[s] = 0.f;

        const float* c1 = ws + C1_OFF + (d*P_ + p)*BG_*S_;
        const float* c2 = ws + C2_OFF + (d*P_ + p)*BG_*S_;
        const float* tg = thetag + (d*P_ + p)*BG_;
        for (int b = 0; b < BG_; ++b) {
            float sx, cx; __sincosf(tg[b] * mp, &sx, &cx);
            #pragma unroll
            for (int s = 0; s < S_; ++s)
                acc[s] += c1[b*S_ + s]*cx - c2[b*S_ + s]*sx;
        }

        float Cm = Bm + pg, invC = 1.f / Cm;
        float sc  = sqrtf(PI_F * invC);
        float bpC = Bm * pg * invC;
        for (int g = 0; g < MG_; ++g) {
            float diff = mp - zgs[g*P_ + p];
            float v = sc * __expf(-bpC*diff*diff);
            #pragma unroll
            for (int s = 0; s < S_; ++s)
                acc[s] += qg[((s*D_ + d)*P_ + p)*MG_ + g] * v;
        }

        #pragma unroll
        for (int s = 0; s < S_; ++s) prod[s] *= E * acc[s];
    }

    // multiply by quAmp and reduce over the 32 m-lanes (full MU in one group)
    #pragma unroll
    for (int s = 0; s < S_; ++s) {
        float val = ws[QUAMP_OFF + (s*D_ + d)*MU_ + m] * prod[s];
        for (int off = 16; off; off >>= 1) val += __shfl_xor(val, off, 32);
        if (m == 0) ws[CANPART_OFF + (s*N_ + n)*D_ + d] = val;
    }
}

// ---------------- final: F_rff + canpart + ts@W ------------------------------
__global__ __launch_bounds__(256) void final_kernel(
    const float* __restrict__ ts, const float* __restrict__ thetau,
    const float* __restrict__ W,  const float* __restrict__ ws,
    float* __restrict__ out)
{
    int tid = blockIdx.x * 256 + threadIdx.x;      // S*N = 8192 threads
    int n = tid & (N_ - 1);
    int s = tid >> 10;

    float t0 = ts[n*P_], t1 = ts[n*P_ + 1], t2 = ts[n*P_ + 2];
    float racc[D_] = {0.f, 0.f, 0.f, 0.f};

    for (int j = 0; j < J_; ++j) {
        const float* thp = thetau + ((s*J_ + j)*P_)*BU_;
        const float* cf  = ws + COEF_OFF + ((s*J_ + j)*BU_)*D_*2;
        for (int bu = 0; bu < BU_; ++bu) {
            float phi = thp[bu]*t0 + thp[BU_ + bu]*t1 + thp[2*BU_ + bu]*t2;
            float sp, cp; __sincosf(phi, &sp, &cp);
            #pragma unroll
            for (int dd = 0; dd < D_; ++dd)
                racc[dd] += cf[(bu*D_ + dd)*2]*cp - cf[(bu*D_ + dd)*2 + 1]*sp;
        }
    }

    #pragma unroll
    for (int dd = 0; dd < D_; ++dd) {
        float w3 = t0*W[0*D_ + dd] + t1*W[1*D_ + dd] + t2*W[2*D_ + dd];
        out[(s*N_ + n)*D_ + dd] =
            ws[CANPART_OFF + (s*N_ + n)*D_ + dd] + racc[dd] + w3;
    }
}

extern "C" void kernel_launch(void* const* d_in, const int* in_sizes, int n_in,
                              void* d_out, int out_size, void* d_ws, size_t ws_size,
                              hipStream_t stream)
{
    const float* ts       = (const float*)d_in[0];
    const float* alphas   = (const float*)d_in[1];
    const float* pgs      = (const float*)d_in[2];
    const float* zgs      = (const float*)d_in[3];
    const float* thetag   = (const float*)d_in[4];
    const float* betag    = (const float*)d_in[5];
    const float* wg       = (const float*)d_in[6];
    const float* qg       = (const float*)d_in[7];
    const float* pus      = (const float*)d_in[8];
    const float* zus      = (const float*)d_in[9];
    const float* thetau   = (const float*)d_in[10];
    const float* betau    = (const float*)d_in[11];
    const float* wu       = (const float*)d_in[12];
    const float* qu       = (const float*)d_in[13];
    const float* ampu     = (const float*)d_in[14];
    const float* log_amps = (const float*)d_in[15];
    const float* W        = (const float*)d_in[16];
    float* ws  = (float*)d_ws;
    float* out = (float*)d_out;

    prep_kernel<<<32, 256, 0, stream>>>(alphas, pgs, zgs, thetag, betag, wg, qg,
                                        pus, thetau, betau, wu, qu, ampu,
                                        log_amps, ws);
    can_kernel<<<512, 256, 0, stream>>>(ts, alphas, pgs, zgs, thetag, qg,
                                        pus, zus, ws);
    final_kernel<<<32, 256, 0, stream>>>(ts, thetau, W, ws, out);
}